// Round 2
// baseline (468.986 us; speedup 1.0000x reference)
//
#include <hip/hip_runtime.h>
#include <math.h>

#define SEQ   4096
#define NOBJ  32
#define IN_F  4
#define HID   64
#define IFEAT 8
#define NPAIR_HALF 496   // 32*31/2 unordered pairs

// tanh(x) = sign(x) * (e^{2|x|}-1)/(e^{2|x|}+1), exact odd symmetry,
// ~1e-7 abs error (v_exp_f32 + v_rcp_f32). Safe at large |x| (e=inf -> t=1).
__device__ __forceinline__ float tanh_fast(float x) {
  float ax = __builtin_fabsf(x);
  float e  = __expf(ax + ax);
  float r  = __builtin_amdgcn_rcpf(e + 1.0f);
  float t  = 1.0f - (r + r);
  return __builtin_copysignf(t, x);
}

// cumulative pair count before row i (i<j ordering): C(i) = i*(63-i)/2
__device__ __forceinline__ int pair_cum(int i) { return (i * (63 - i)) >> 1; }

__global__ __launch_bounds__(256, 8) void magnet_fused(
    const float* __restrict__ x,      // [S,32,4]
    const float* __restrict__ L1W,    // [64,4]
    const float* __restrict__ L1b,    // [64]
    const float* __restrict__ L2W,    // [64,64]
    const float* __restrict__ L2b,    // [64]
    const float* __restrict__ I1W,    // [64,64]
    const float* __restrict__ I2W,    // [8,64]
    const float* __restrict__ I3,     // [992,2,4]
    const float* __restrict__ S1W,    // [4,4]
    const float* __restrict__ S1b,    // [4]
    const float* __restrict__ S2W,    // [32,2,2]
    const float* __restrict__ S2b,    // [32,2]
    float* __restrict__ out)          // [S,32,2]
{
  // One buffer, two aliased views:
  //   region A (first 64*36 floats): sAt in phases 1-2, then sg in phases 3-4
  //     (sg needs 32*65=2080 floats <= 64*36=2304; sAt dead after phase 2,
  //      __syncthreads separates phase 2 reads from phase 3 writes)
  //   region B (next 64*36 floats): sBt (phase 2 write, phase 3 read)
  __shared__ __align__(16) float smem[2 * HID * 36];
  float (*sAt)[36] = (float(*)[36])smem;
  float (*sBt)[36] = (float(*)[36])(smem + HID * 36);
  float (*sg)[65]  = (float(*)[65])smem;   // aliases sAt
  __shared__ float sx[NOBJ][IN_F];
  __shared__ float sacc[NOBJ][2];

  const int t = threadIdx.x;
  const int s = blockIdx.x;

  if (t < NOBJ * IN_F) ((float*)sx)[t] = x[s * (NOBJ * IN_F) + t];
  if (t < NOBJ * 2)    ((float*)sacc)[t] = 0.0f;
  __syncthreads();

  // ---- phase 1: h1 = relu(x @ L1W^T + L1b) -> sAt[k][n] ----
  {
    const int n = t & 31, kb = (t >> 5) * 8;
    const float x0 = sx[n][0], x1 = sx[n][1], x2 = sx[n][2], x3 = sx[n][3];
    #pragma unroll
    for (int r = 0; r < 8; ++r) {
      const int k = kb + r;
      const float4 w = *(const float4*)(L1W + k * 4);
      float a = L1b[k];
      a = fmaf(x0, w.x, a); a = fmaf(x1, w.y, a);
      a = fmaf(x2, w.z, a); a = fmaf(x3, w.w, a);
      sAt[k][n] = fmaxf(a, 0.0f);
    }
  }
  __syncthreads();

  const int ho = t & 63;
  const int nb = (t >> 6) * 8;

  // ---- phase 2: h2 = relu(h1 @ L2W^T + L2b) -> sBt[ho][n] ----
  {
    float acc[8];
    const float b = L2b[ho];
    #pragma unroll
    for (int r = 0; r < 8; ++r) acc[r] = b;
    const float* wr = L2W + ho * HID;
    #pragma unroll
    for (int k4 = 0; k4 < HID; k4 += 4) {
      const float4 w = *(const float4*)(wr + k4);
      #pragma unroll
      for (int kk = 0; kk < 4; ++kk) {
        const float wk = (&w.x)[kk];
        const float4 a0 = *(const float4*)&sAt[k4 + kk][nb];
        const float4 a1 = *(const float4*)&sAt[k4 + kk][nb + 4];
        acc[0] = fmaf(wk, a0.x, acc[0]); acc[1] = fmaf(wk, a0.y, acc[1]);
        acc[2] = fmaf(wk, a0.z, acc[2]); acc[3] = fmaf(wk, a0.w, acc[3]);
        acc[4] = fmaf(wk, a1.x, acc[4]); acc[5] = fmaf(wk, a1.y, acc[5]);
        acc[6] = fmaf(wk, a1.z, acc[6]); acc[7] = fmaf(wk, a1.w, acc[7]);
      }
    }
    #pragma unroll
    for (int r = 0; r < 8; ++r) sBt[ho][nb + r] = fmaxf(acc[r], 0.0f);
  }
  __syncthreads();

  // ---- phase 3: g = h2 @ I1W^T -> sg[n][ho] (no bias / relu) ----
  // sg aliases sAt; sAt fully consumed in phase 2, barrier above protects.
  {
    float acc[8] = {0.f,0.f,0.f,0.f,0.f,0.f,0.f,0.f};
    const float* wr = I1W + ho * HID;
    #pragma unroll
    for (int k4 = 0; k4 < HID; k4 += 4) {
      const float4 w = *(const float4*)(wr + k4);
      #pragma unroll
      for (int kk = 0; kk < 4; ++kk) {
        const float wk = (&w.x)[kk];
        const float4 a0 = *(const float4*)&sBt[k4 + kk][nb];
        const float4 a1 = *(const float4*)&sBt[k4 + kk][nb + 4];
        acc[0] = fmaf(wk, a0.x, acc[0]); acc[1] = fmaf(wk, a0.y, acc[1]);
        acc[2] = fmaf(wk, a0.z, acc[2]); acc[3] = fmaf(wk, a0.w, acc[3]);
        acc[4] = fmaf(wk, a1.x, acc[4]); acc[5] = fmaf(wk, a1.y, acc[5]);
        acc[6] = fmaf(wk, a1.z, acc[6]); acc[7] = fmaf(wk, a1.w, acc[7]);
      }
    }
    #pragma unroll
    for (int r = 0; r < 8; ++r) sg[nb + r][ho] = acc[r];
  }
  __syncthreads();

  // ---- phase 4: unordered pairs (i<j); antisymmetry gives (j,i) for free ----
  for (int q = t; q < NPAIR_HALF; q += 256) {
    // closed-form row index: solve i*(63-i)/2 <= q < (i+1)*(62-i)/2
    int i = (int)((63.0f - sqrtf(3969.0f - 8.0f * (float)q)) * 0.5f);
    if (i > 0 && pair_cum(i) > q) --i;            // fp rounding fixup
    if (pair_cum(i + 1) <= q)     ++i;
    const int j = i + 1 + (q - pair_cum(i));

    float u[IFEAT] = {0.f,0.f,0.f,0.f,0.f,0.f,0.f,0.f};
    #pragma unroll 16
    for (int h = 0; h < HID; ++h) {
      const float d  = sg[i][h] - sg[j][h];
      const float th = tanh_fast(d);
      #pragma unroll
      for (int f = 0; f < IFEAT; ++f)         // I2W index lane-uniform -> s_load
        u[f] = fmaf(I2W[f * HID + h], th, u[f]);
    }

    // row-major pair table index: p(a,b) = a*31 + b - (b>a)
    const float* cij = I3 + (i * 31 + (j - 1)) * 8;   // j > i
    const float* cji = I3 + (j * 31 + i) * 8;         // i < j
    #pragma unroll
    for (int d = 0; d < 2; ++d) {
      float vi = 0.f, vj = 0.f;
      #pragma unroll
      for (int k = 0; k < 4; ++k) {
        const float v = tanh_fast(u[d * 4 + k]);
        vi = fmaf(cij[d * 4 + k],  v, vi);
        vj = fmaf(cji[d * 4 + k], -v, vj);
      }
      atomicAdd(&sacc[i][d], vi);
      atomicAdd(&sacc[j][d], vj);
    }
  }
  __syncthreads();

  // ---- epilogue: self term + store ----
  if (t < NOBJ * 2) {
    const int i = t >> 1, d = t & 1;
    float res = S2b[t] + sacc[i][d];
    #pragma unroll
    for (int k = 0; k < 2; ++k) {
      const int f = d * 2 + k;
      float hs = S1b[f];
      hs = fmaf(sx[i][0], S1W[f * 4 + 0], hs);
      hs = fmaf(sx[i][1], S1W[f * 4 + 1], hs);
      hs = fmaf(sx[i][2], S1W[f * 4 + 2], hs);
      hs = fmaf(sx[i][3], S1W[f * 4 + 3], hs);
      hs = fmaxf(hs, 0.0f);
      res = fmaf(hs, S2W[i * 4 + d * 2 + k], res);
    }
    out[s * (NOBJ * 2) + t] = res;
  }
}

extern "C" void kernel_launch(void* const* d_in, const int* in_sizes, int n_in,
                              void* d_out, int out_size, void* d_ws, size_t ws_size,
                              hipStream_t stream) {
  const float* x   = (const float*)d_in[0];
  const float* L1W = (const float*)d_in[1];
  const float* L1b = (const float*)d_in[2];
  const float* L2W = (const float*)d_in[3];
  const float* L2b = (const float*)d_in[4];
  const float* I1W = (const float*)d_in[5];
  const float* I2W = (const float*)d_in[6];
  const float* I3  = (const float*)d_in[7];
  const float* S1W = (const float*)d_in[8];
  const float* S1b = (const float*)d_in[9];
  const float* S2W = (const float*)d_in[10];
  const float* S2b = (const float*)d_in[11];
  float* outp = (float*)d_out;

  magnet_fused<<<SEQ, 256, 0, stream>>>(x, L1W, L1b, L2W, L2b, I1W, I2W, I3,
                                        S1W, S1b, S2W, S2b, outp);
}

// Round 3
// 210.779 us; speedup vs baseline: 2.2250x; 2.2250x over previous
//
#include <hip/hip_runtime.h>
#include <math.h>

#define SEQ   4096
#define NOBJ  32
#define IN_F  4
#define HID   64
#define IFEAT 8
#define NPAIR_HALF 496   // 32*31/2 unordered pairs

// tanh(x) = sign(x) * (e^{2|x|}-1)/(e^{2|x|}+1), exact odd symmetry,
// ~1e-7 abs error (v_exp_f32 + v_rcp_f32). Safe at large |x| (e=inf -> t=1).
__device__ __forceinline__ float tanh_fast(float x) {
  float ax = __builtin_fabsf(x);
  float e  = __expf(ax + ax);
  float r  = __builtin_amdgcn_rcpf(e + 1.0f);
  float t  = 1.0f - (r + r);
  return __builtin_copysignf(t, x);
}

// cumulative pair count before row i (i<j ordering): C(i) = i*(63-i)/2
__device__ __forceinline__ int pair_cum(int i) { return (i * (63 - i)) >> 1; }

// launch_bounds: (256,4) = VGPR cap 128. (256,8) forced VGPR<=64 -> 30MB of
// scratch spills per dispatch (R1: WRITE_SIZE 31MB, dur 425us). LDS (19456B)
// caps occupancy at 8 blocks/CU anyway; don't starve the allocator.
__global__ __launch_bounds__(256, 4) void magnet_fused(
    const float* __restrict__ x,      // [S,32,4]
    const float* __restrict__ L1W,    // [64,4]
    const float* __restrict__ L1b,    // [64]
    const float* __restrict__ L2W,    // [64,64]
    const float* __restrict__ L2b,    // [64]
    const float* __restrict__ I1W,    // [64,64]
    const float* __restrict__ I2W,    // [8,64]
    const float* __restrict__ I3,     // [992,2,4]
    const float* __restrict__ S1W,    // [4,4]
    const float* __restrict__ S1b,    // [4]
    const float* __restrict__ S2W,    // [32,2,2]
    const float* __restrict__ S2b,    // [32,2]
    float* __restrict__ out)          // [S,32,2]
{
  // One buffer, two aliased views:
  //   region A (first 64*36 floats): sAt in phases 1-2, then sg in phases 3-4
  //     (sg needs 32*65=2080 floats <= 64*36=2304; sAt dead after phase 2,
  //      __syncthreads separates phase 2 reads from phase 3 writes)
  //   region B (next 64*36 floats): sBt (phase 2 write, phase 3 read)
  __shared__ __align__(16) float smem[2 * HID * 36];
  float (*sAt)[36] = (float(*)[36])smem;
  float (*sBt)[36] = (float(*)[36])(smem + HID * 36);
  float (*sg)[65]  = (float(*)[65])smem;   // aliases sAt
  __shared__ float sx[NOBJ][IN_F];
  __shared__ float sacc[NOBJ][2];

  const int t = threadIdx.x;
  const int s = blockIdx.x;

  if (t < NOBJ * IN_F) ((float*)sx)[t] = x[s * (NOBJ * IN_F) + t];
  if (t < NOBJ * 2)    ((float*)sacc)[t] = 0.0f;
  __syncthreads();

  // ---- phase 1: h1 = relu(x @ L1W^T + L1b) -> sAt[k][n] ----
  {
    const int n = t & 31, kb = (t >> 5) * 8;
    const float x0 = sx[n][0], x1 = sx[n][1], x2 = sx[n][2], x3 = sx[n][3];
    #pragma unroll
    for (int r = 0; r < 8; ++r) {
      const int k = kb + r;
      const float4 w = *(const float4*)(L1W + k * 4);
      float a = L1b[k];
      a = fmaf(x0, w.x, a); a = fmaf(x1, w.y, a);
      a = fmaf(x2, w.z, a); a = fmaf(x3, w.w, a);
      sAt[k][n] = fmaxf(a, 0.0f);
    }
  }
  __syncthreads();

  const int ho = t & 63;
  const int nb = (t >> 6) * 8;

  // ---- phase 2: h2 = relu(h1 @ L2W^T + L2b) -> sBt[ho][n] ----
  {
    float acc[8];
    const float b = L2b[ho];
    #pragma unroll
    for (int r = 0; r < 8; ++r) acc[r] = b;
    const float* wr = L2W + ho * HID;
    #pragma unroll
    for (int k4 = 0; k4 < HID; k4 += 4) {
      const float4 w = *(const float4*)(wr + k4);
      #pragma unroll
      for (int kk = 0; kk < 4; ++kk) {
        const float wk = (&w.x)[kk];
        const float4 a0 = *(const float4*)&sAt[k4 + kk][nb];
        const float4 a1 = *(const float4*)&sAt[k4 + kk][nb + 4];
        acc[0] = fmaf(wk, a0.x, acc[0]); acc[1] = fmaf(wk, a0.y, acc[1]);
        acc[2] = fmaf(wk, a0.z, acc[2]); acc[3] = fmaf(wk, a0.w, acc[3]);
        acc[4] = fmaf(wk, a1.x, acc[4]); acc[5] = fmaf(wk, a1.y, acc[5]);
        acc[6] = fmaf(wk, a1.z, acc[6]); acc[7] = fmaf(wk, a1.w, acc[7]);
      }
    }
    #pragma unroll
    for (int r = 0; r < 8; ++r) sBt[ho][nb + r] = fmaxf(acc[r], 0.0f);
  }
  __syncthreads();

  // ---- phase 3: g = h2 @ I1W^T -> sg[n][ho] (no bias / relu) ----
  // sg aliases sAt; sAt fully consumed in phase 2, barrier above protects.
  {
    float acc[8] = {0.f,0.f,0.f,0.f,0.f,0.f,0.f,0.f};
    const float* wr = I1W + ho * HID;
    #pragma unroll
    for (int k4 = 0; k4 < HID; k4 += 4) {
      const float4 w = *(const float4*)(wr + k4);
      #pragma unroll
      for (int kk = 0; kk < 4; ++kk) {
        const float wk = (&w.x)[kk];
        const float4 a0 = *(const float4*)&sBt[k4 + kk][nb];
        const float4 a1 = *(const float4*)&sBt[k4 + kk][nb + 4];
        acc[0] = fmaf(wk, a0.x, acc[0]); acc[1] = fmaf(wk, a0.y, acc[1]);
        acc[2] = fmaf(wk, a0.z, acc[2]); acc[3] = fmaf(wk, a0.w, acc[3]);
        acc[4] = fmaf(wk, a1.x, acc[4]); acc[5] = fmaf(wk, a1.y, acc[5]);
        acc[6] = fmaf(wk, a1.z, acc[6]); acc[7] = fmaf(wk, a1.w, acc[7]);
      }
    }
    #pragma unroll
    for (int r = 0; r < 8; ++r) sg[nb + r][ho] = acc[r];
  }
  __syncthreads();

  // ---- phase 4: unordered pairs (i<j); antisymmetry gives (j,i) for free ----
  for (int q = t; q < NPAIR_HALF; q += 256) {
    // closed-form row index: solve i*(63-i)/2 <= q < (i+1)*(62-i)/2
    int i = (int)((63.0f - sqrtf(3969.0f - 8.0f * (float)q)) * 0.5f);
    if (i > 0 && pair_cum(i) > q) --i;            // fp rounding fixup
    if (pair_cum(i + 1) <= q)     ++i;
    const int j = i + 1 + (q - pair_cum(i));

    float u[IFEAT] = {0.f,0.f,0.f,0.f,0.f,0.f,0.f,0.f};
    #pragma unroll 16
    for (int h = 0; h < HID; ++h) {
      const float d  = sg[i][h] - sg[j][h];
      const float th = tanh_fast(d);
      #pragma unroll
      for (int f = 0; f < IFEAT; ++f)         // I2W index lane-uniform -> s_load
        u[f] = fmaf(I2W[f * HID + h], th, u[f]);
    }

    // row-major pair table index: p(a,b) = a*31 + b - (b>a)
    const float* cij = I3 + (i * 31 + (j - 1)) * 8;   // j > i
    const float* cji = I3 + (j * 31 + i) * 8;         // i < j
    #pragma unroll
    for (int d = 0; d < 2; ++d) {
      float vi = 0.f, vj = 0.f;
      #pragma unroll
      for (int k = 0; k < 4; ++k) {
        const float v = tanh_fast(u[d * 4 + k]);
        vi = fmaf(cij[d * 4 + k],  v, vi);
        vj = fmaf(cji[d * 4 + k], -v, vj);
      }
      atomicAdd(&sacc[i][d], vi);
      atomicAdd(&sacc[j][d], vj);
    }
  }
  __syncthreads();

  // ---- epilogue: self term + store ----
  if (t < NOBJ * 2) {
    const int i = t >> 1, d = t & 1;
    float res = S2b[t] + sacc[i][d];
    #pragma unroll
    for (int k = 0; k < 2; ++k) {
      const int f = d * 2 + k;
      float hs = S1b[f];
      hs = fmaf(sx[i][0], S1W[f * 4 + 0], hs);
      hs = fmaf(sx[i][1], S1W[f * 4 + 1], hs);
      hs = fmaf(sx[i][2], S1W[f * 4 + 2], hs);
      hs = fmaf(sx[i][3], S1W[f * 4 + 3], hs);
      hs = fmaxf(hs, 0.0f);
      res = fmaf(hs, S2W[i * 4 + d * 2 + k], res);
    }
    out[s * (NOBJ * 2) + t] = res;
  }
}

extern "C" void kernel_launch(void* const* d_in, const int* in_sizes, int n_in,
                              void* d_out, int out_size, void* d_ws, size_t ws_size,
                              hipStream_t stream) {
  const float* x   = (const float*)d_in[0];
  const float* L1W = (const float*)d_in[1];
  const float* L1b = (const float*)d_in[2];
  const float* L2W = (const float*)d_in[3];
  const float* L2b = (const float*)d_in[4];
  const float* I1W = (const float*)d_in[5];
  const float* I2W = (const float*)d_in[6];
  const float* I3  = (const float*)d_in[7];
  const float* S1W = (const float*)d_in[8];
  const float* S1b = (const float*)d_in[9];
  const float* S2W = (const float*)d_in[10];
  const float* S2b = (const float*)d_in[11];
  float* outp = (float*)d_out;

  magnet_fused<<<SEQ, 256, 0, stream>>>(x, L1W, L1b, L2W, L2b, I1W, I2W, I3,
                                        S1W, S1b, S2W, S2b, outp);
}